// Round 9
// baseline (639.566 us; speedup 1.0000x reference)
//
#include <hip/hip_runtime.h>

#define BLK 256

// broadcast lane l of v across the wave (l wave-uniform; dynamic is legal)
__device__ __forceinline__ float bcast(float v, int l) {
    return __int_as_float(__builtin_amdgcn_readlane(__float_as_int(v), l));
}
// fp32 <-> bf16 (round-to-nearest-even)
__device__ __forceinline__ unsigned short f2bf(float f) {
    unsigned u = __float_as_uint(f);
    return (unsigned short)((u + 0x7FFFu + ((u >> 16) & 1u)) >> 16);
}
__device__ __forceinline__ float bf2f(unsigned short b) {
    return __uint_as_float(((unsigned)b) << 16);
}

// ================= batched CSR skeleton (all 4 graphs) =================
// hist returns each edge's rank within its dst (ushort) so fill needs no atomics.

__global__ void k_hist_all(const int* __restrict__ dv, const int* __restrict__ dh,
                           const int* __restrict__ di, const int* __restrict__ ds,
                           int* __restrict__ cv, int* __restrict__ ch,
                           int* __restrict__ ci, int* __restrict__ cs,
                           unsigned short* __restrict__ rkv, unsigned short* __restrict__ rkh,
                           unsigned short* __restrict__ rki, unsigned short* __restrict__ rks,
                           int Ev, int Eh, int Ei, int Es) {
    int e = blockIdx.x * blockDim.x + threadIdx.x;
    if (e < Ev) { rkv[e] = (unsigned short)atomicAdd(&cv[dv[e]], 1); return; }
    e -= Ev;
    if (e < Eh) { rkh[e] = (unsigned short)atomicAdd(&ch[dh[e]], 1); return; }
    e -= Eh;
    if (e < Ei) { rki[e] = (unsigned short)atomicAdd(&ci[di[e]], 1); return; }
    e -= Ei;
    if (e < Es) rks[e] = (unsigned short)atomicAdd(&cs[ds[e]], 1);
}

__global__ void k_scanb_all(const int* __restrict__ cv, const int* __restrict__ ch,
                            const int* __restrict__ ci, const int* __restrict__ cs,
                            int* __restrict__ rv, int* __restrict__ rh,
                            int* __restrict__ ri, int* __restrict__ rs,
                            float* __restrict__ dv, float* __restrict__ ds,
                            int* __restrict__ bsum, int nv, int ns, int nbv, int nbs) {
    __shared__ int sh[256];
    int blk = blockIdx.x;
    const int* cnt; int* rp; float* dinv; int n; int lb;
    if (blk < nbv)                { cnt = cv; rp = rv; dinv = dv;      n = nv; lb = blk; }
    else if (blk < nbv + nbs)     { cnt = ch; rp = rh; dinv = nullptr; n = ns; lb = blk - nbv; }
    else if (blk < nbv + 2 * nbs) { cnt = ci; rp = ri; dinv = nullptr; n = ns; lb = blk - nbv - nbs; }
    else                          { cnt = cs; rp = rs; dinv = ds;      n = ns; lb = blk - nbv - 2 * nbs; }
    int i = lb * 256 + threadIdx.x;
    int v = (i < n) ? cnt[i] : 0;
    if (dinv && i < n) dinv[i] = v > 0 ? rsqrtf((float)v) : 0.f;
    sh[threadIdx.x] = v; __syncthreads();
    for (int off = 1; off < 256; off <<= 1) {
        int t = (threadIdx.x >= off) ? sh[threadIdx.x - off] : 0;
        __syncthreads();
        sh[threadIdx.x] += t; __syncthreads();
    }
    if (i < n) rp[i] = sh[threadIdx.x] - v;
    if (threadIdx.x == 255) bsum[blk] = sh[255];
}

__global__ void k_scant_all(int* __restrict__ bsum, int nbv, int nbs) {
    __shared__ int sh[1024];
    int g = blockIdx.x;
    int off = (g == 0) ? 0 : nbv + (g - 1) * nbs;
    int nb  = (g == 0) ? nbv : nbs;
    int tid = threadIdx.x;
    int v = (tid < nb) ? bsum[off + tid] : 0;
    sh[tid] = v; __syncthreads();
    for (int o2 = 1; o2 < 1024; o2 <<= 1) {
        int t = (tid >= o2) ? sh[tid - o2] : 0;
        __syncthreads();
        sh[tid] += t; __syncthreads();
    }
    if (tid < nb) bsum[off + tid] = sh[tid] - v;
}

__global__ void k_scana_all(int* __restrict__ rv, int* __restrict__ rh,
                            int* __restrict__ ri, int* __restrict__ rs,
                            const int* __restrict__ bsum, int nv, int ns, int nbv, int nbs,
                            int Ev, int Eh, int Ei, int Es) {
    int blk = blockIdx.x;
    int* rp; int n; int lb; int E;
    if (blk < nbv)                { rp = rv; n = nv; lb = blk;               E = Ev; }
    else if (blk < nbv + nbs)     { rp = rh; n = ns; lb = blk - nbv;         E = Eh; }
    else if (blk < nbv + 2 * nbs) { rp = ri; n = ns; lb = blk - nbv - nbs;   E = Ei; }
    else                          { rp = rs; n = ns; lb = blk - nbv - 2*nbs; E = Es; }
    int i = lb * 256 + threadIdx.x;
    if (i < n) rp[i] += bsum[blk];
    if (i == 0) rp[n] = E;
}

__global__ void k_fill_all(
    const int* __restrict__ vv_s, const int* __restrict__ vv_d,
    const unsigned short* __restrict__ rkv, const int* __restrict__ rv, int* __restrict__ vvsrc,
    const int* __restrict__ h_s, const int* __restrict__ h_d, const float* __restrict__ hw,
    const unsigned short* __restrict__ rkh, const int* __restrict__ rh, int2* __restrict__ hsw,
    const int* __restrict__ in_s, const int* __restrict__ in_d,
    const unsigned short* __restrict__ rki, const int* __restrict__ ri, int* __restrict__ insrc,
    const int* __restrict__ ss_s, const int* __restrict__ ss_d,
    const unsigned short* __restrict__ rks, const int* __restrict__ rs, int* __restrict__ sssrc,
    int Ev, int Eh, int Ei, int Es) {
    int e = blockIdx.x * blockDim.x + threadIdx.x;
    if (e < Ev) { vvsrc[rv[vv_d[e]] + rkv[e]] = vv_s[e]; return; }
    e -= Ev;
    if (e < Eh) { hsw[rh[h_d[e]] + rkh[e]] = make_int2(h_s[e], __float_as_int(hw[e])); return; }
    e -= Eh;
    if (e < Ei) { insrc[ri[in_d[e]] + rki[e]] = in_s[e]; return; }
    e -= Ei;
    if (e < Es) sssrc[rs[ss_d[e]] + rks[e]] = ss_s[e];
}

// ================= stage-A gathers =================

__global__ void k_gather5(const float* __restrict__ x, const int* __restrict__ rowptr,
                          const int* __restrict__ csr_src, const float* __restrict__ dinv,
                          float* __restrict__ out, int n) {
    int d = blockIdx.x * blockDim.x + threadIdx.x;
    if (d >= n) return;
    int b = rowptr[d], e = rowptr[d + 1];
    float dd = dinv[d];
    float a0 = 0, a1 = 0, a2 = 0, a3 = 0, a4 = 0;
    int p = b;
    for (; p + 4 <= e; p += 4) {
        int s0 = csr_src[p], s1 = csr_src[p+1], s2 = csr_src[p+2], s3 = csr_src[p+3];
        const float* x0 = x + (size_t)s0 * 5;
        const float* x1 = x + (size_t)s1 * 5;
        const float* x2 = x + (size_t)s2 * 5;
        const float* x3 = x + (size_t)s3 * 5;
        float w0 = dd * dinv[s0], w1 = dd * dinv[s1], w2 = dd * dinv[s2], w3 = dd * dinv[s3];
        a0 += x0[0]*w0 + x1[0]*w1 + x2[0]*w2 + x3[0]*w3;
        a1 += x0[1]*w0 + x1[1]*w1 + x2[1]*w2 + x3[1]*w3;
        a2 += x0[2]*w0 + x1[2]*w1 + x2[2]*w2 + x3[2]*w3;
        a3 += x0[3]*w0 + x1[3]*w1 + x2[3]*w2 + x3[3]*w3;
        a4 += x0[4]*w0 + x1[4]*w1 + x2[4]*w2 + x3[4]*w3;
    }
    for (; p < e; p++) {
        int s = csr_src[p];
        float w = dd * dinv[s];
        const float* xp = x + (size_t)s * 5;
        a0 += xp[0]*w; a1 += xp[1]*w; a2 += xp[2]*w; a3 += xp[3]*w; a4 += xp[4]*w;
    }
    float* op = out + (size_t)d * 5;
    op[0] = a0; op[1] = a1; op[2] = a2; op[3] = a3; op[4] = a4;
}

// in-register bf16 row gather: 4 groups x 16 lanes x ushort4; 4-edge-deep MLP;
// returns the fully butterflied float4 (all lanes hold the group-summed slice for their q).
// MODE: 0 = plain sum, 1 = per-edge weight (int2 packed), 2 = symmetric gcn norm
template<int MODE>
__device__ __forceinline__ float4 gather_row(
        const unsigned short* __restrict__ xbf, int b, int e, int g, int q,
        const int* __restrict__ csr_src, const int2* __restrict__ csr_sw,
        const float* __restrict__ dinv, float dd) {
    float4 acc = make_float4(0.f, 0.f, 0.f, 0.f);
    int p = b + g;
    for (; p + 12 < e; p += 16) {
        int s0, s1, s2, s3;
        float w0 = 1.f, w1 = 1.f, w2 = 1.f, w3 = 1.f;
        if (MODE == 1) {
            int2 e0 = csr_sw[p], e1 = csr_sw[p+4], e2 = csr_sw[p+8], e3 = csr_sw[p+12];
            s0 = e0.x; w0 = __int_as_float(e0.y);
            s1 = e1.x; w1 = __int_as_float(e1.y);
            s2 = e2.x; w2 = __int_as_float(e2.y);
            s3 = e3.x; w3 = __int_as_float(e3.y);
        } else {
            s0 = csr_src[p]; s1 = csr_src[p+4]; s2 = csr_src[p+8]; s3 = csr_src[p+12];
            if (MODE == 2) {
                w0 = dd * dinv[s0]; w1 = dd * dinv[s1];
                w2 = dd * dinv[s2]; w3 = dd * dinv[s3];
            }
        }
        ushort4 u0 = ((const ushort4*)(xbf + (size_t)s0 * 64))[q];
        ushort4 u1 = ((const ushort4*)(xbf + (size_t)s1 * 64))[q];
        ushort4 u2 = ((const ushort4*)(xbf + (size_t)s2 * 64))[q];
        ushort4 u3 = ((const ushort4*)(xbf + (size_t)s3 * 64))[q];
        acc.x += bf2f(u0.x)*w0 + bf2f(u1.x)*w1 + bf2f(u2.x)*w2 + bf2f(u3.x)*w3;
        acc.y += bf2f(u0.y)*w0 + bf2f(u1.y)*w1 + bf2f(u2.y)*w2 + bf2f(u3.y)*w3;
        acc.z += bf2f(u0.z)*w0 + bf2f(u1.z)*w1 + bf2f(u2.z)*w2 + bf2f(u3.z)*w3;
        acc.w += bf2f(u0.w)*w0 + bf2f(u1.w)*w1 + bf2f(u2.w)*w2 + bf2f(u3.w)*w3;
    }
    for (; p < e; p += 4) {
        int s; float w = 1.f;
        if (MODE == 1) { int2 e0 = csr_sw[p]; s = e0.x; w = __int_as_float(e0.y); }
        else { s = csr_src[p]; if (MODE == 2) w = dd * dinv[s]; }
        ushort4 u = ((const ushort4*)(xbf + (size_t)s * 64))[q];
        acc.x += bf2f(u.x)*w; acc.y += bf2f(u.y)*w;
        acc.z += bf2f(u.z)*w; acc.w += bf2f(u.w)*w;
    }
    #pragma unroll
    for (int off = 16; off < 64; off <<= 1) {
        acc.x += __shfl_xor(acc.x, off, 64);
        acc.y += __shfl_xor(acc.y, off, 64);
        acc.z += __shfl_xor(acc.z, off, 64);
        acc.w += __shfl_xor(acc.w, off, 64);
    }
    return acc;  // all lanes: slice [4q..4q+3] of the summed row
}

// ================= fused stage B+C: wave per s-row =================
// agg = EH-weighted gather(gx); ssum = EIN gather(gx);
// sx = relu(gc_b + agg@Wrel + st@Wroot); sx2 = relu(bl + (ssum/cnt)@Wl + sx@Wr);
// sx3 = tag2_b + sx2@W0;  write sx2 (bf16) and sx3 (fp32).
__global__ __launch_bounds__(256, 4)
void k_bc(const unsigned short* __restrict__ gx,
          const int* __restrict__ rh, const int2* __restrict__ hsw,
          const int* __restrict__ ri, const int* __restrict__ insrc,
          const float* __restrict__ st,
          const float* __restrict__ Wrel, const float* __restrict__ Wroot,
          const float* __restrict__ gc_b,
          const float* __restrict__ Wl, const float* __restrict__ Wr,
          const float* __restrict__ bl,
          const float* __restrict__ W0, const float* __restrict__ tag2_b,
          unsigned short* __restrict__ sx2_bf, float* __restrict__ sx3, int n) {
    int wid = (int)(((long long)blockIdx.x * blockDim.x + threadIdx.x) >> 6);
    if (wid >= n) return;
    int lane = threadIdx.x & 63;
    int g = lane >> 4, q = lane & 15;

    int hb = rh[wid], he = rh[wid + 1];
    int ib = ri[wid], ie = ri[wid + 1];
    float4 aggv = gather_row<1>(gx, hb, he, g, q, nullptr, hsw, nullptr, 0.f);
    float4 sumv = gather_row<0>(gx, ib, ie, g, q, insrc, nullptr, nullptr, 0.f);
    float rs = 1.f / fmaxf((float)(ie - ib), 1.f);

    float srow = (lane < 6) ? st[(size_t)wid * 6 + lane] : 0.f;

    // sx = relu(gc_b + agg@Wrel + st@Wroot)
    float sx = gc_b[lane];
    #pragma unroll 4
    for (int qq = 0; qq < 16; qq++) {
        float r0 = bcast(aggv.x, qq), r1 = bcast(aggv.y, qq);
        float r2 = bcast(aggv.z, qq), r3 = bcast(aggv.w, qq);
        int k = qq * 4;
        sx += r0 * Wrel[(k    ) * 64 + lane] + r1 * Wrel[(k + 1) * 64 + lane]
            + r2 * Wrel[(k + 2) * 64 + lane] + r3 * Wrel[(k + 3) * 64 + lane];
    }
    #pragma unroll
    for (int k = 0; k < 6; k++)
        sx += bcast(srow, k) * Wroot[k * 64 + lane];
    sx = fmaxf(sx, 0.f);

    // sx2 = relu(bl + (ssum*rs)@Wl + sx@Wr)
    float sx2 = bl[lane];
    #pragma unroll 4
    for (int qq = 0; qq < 16; qq++) {
        float m0 = bcast(sumv.x, qq) * rs, m1 = bcast(sumv.y, qq) * rs;
        float m2 = bcast(sumv.z, qq) * rs, m3 = bcast(sumv.w, qq) * rs;
        int k = qq * 4;
        sx2 += m0 * Wl[(k    ) * 64 + lane] + m1 * Wl[(k + 1) * 64 + lane]
             + m2 * Wl[(k + 2) * 64 + lane] + m3 * Wl[(k + 3) * 64 + lane];
    }
    #pragma unroll 8
    for (int k = 0; k < 64; k++)
        sx2 += bcast(sx, k) * Wr[k * 64 + lane];
    sx2 = fmaxf(sx2, 0.f);

    // sx3 = tag2_b + sx2@W0
    float s3 = tag2_b[lane];
    #pragma unroll 8
    for (int k = 0; k < 64; k++)
        s3 += bcast(sx2, k) * W0[k * 64 + lane];

    sx2_bf[(size_t)wid * 64 + lane] = f2bf(sx2);
    sx3[(size_t)wid * 64 + lane] = s3;
}

// ================= fused stage-D hop: wave per s-row =================
// h = gcn-gather(xin); write h (bf16, for next hop); sx3 += h@W.
__global__ __launch_bounds__(256, 4)
void k_hop(const unsigned short* __restrict__ xin,
           const int* __restrict__ rs, const int* __restrict__ sssrc,
           const float* __restrict__ dinv,
           const float* __restrict__ W,
           unsigned short* __restrict__ hout, float* __restrict__ sx3, int n) {
    int wid = (int)(((long long)blockIdx.x * blockDim.x + threadIdx.x) >> 6);
    if (wid >= n) return;
    int lane = threadIdx.x & 63;
    int g = lane >> 4, q = lane & 15;
    int b = rs[wid], e = rs[wid + 1];
    float dd = dinv[wid];
    float4 h = gather_row<2>(xin, b, e, g, q, sssrc, nullptr, dinv, dd);

    if (g == 0) {
        ushort4 ov;
        ov.x = f2bf(h.x); ov.y = f2bf(h.y); ov.z = f2bf(h.z); ov.w = f2bf(h.w);
        ((ushort4*)hout)[(size_t)wid * 16 + q] = ov;
    }

    float acc = 0.f;
    #pragma unroll 4
    for (int qq = 0; qq < 16; qq++) {
        float r0 = bcast(h.x, qq), r1 = bcast(h.y, qq);
        float r2 = bcast(h.z, qq), r3 = bcast(h.w, qq);
        int k = qq * 4;
        acc += r0 * W[(k    ) * 64 + lane] + r1 * W[(k + 1) * 64 + lane]
             + r2 * W[(k + 2) * 64 + lane] + r3 * W[(k + 3) * 64 + lane];
    }
    sx3[(size_t)wid * 64 + lane] += acc;
}

// ================= stage-A dense combine =================

__global__ __launch_bounds__(256, 4)
void k_tag1_w(const float* __restrict__ x, const float* __restrict__ h1,
              const float* __restrict__ h2, const float* __restrict__ W,
              const float* __restrict__ b, unsigned short* __restrict__ out, int n) {
    int wv = (int)(((long long)blockIdx.x * blockDim.x + threadIdx.x) >> 6);
    int lane = threadIdx.x & 63;
    int i0 = wv * 4;
    if (i0 >= n) return;
    float v[4], acc[4];
    #pragma unroll
    for (int r = 0; r < 4; r++) {
        int i = (i0 + r < n) ? i0 + r : n - 1;
        float t = 0.f;
        if (lane < 5)                     t = x [(size_t)i * 5 + lane];
        else if (lane >= 8 && lane < 13)  t = h1[(size_t)i * 5 + lane - 8];
        else if (lane >= 16 && lane < 21) t = h2[(size_t)i * 5 + lane - 16];
        v[r] = t;
        acc[r] = b[lane];
    }
    #pragma unroll
    for (int m = 0; m < 3; m++) {
        #pragma unroll
        for (int k = 0; k < 5; k++) {
            float wk = W[(m * 5 + k) * 64 + lane];
            #pragma unroll
            for (int r = 0; r < 4; r++) acc[r] += bcast(v[r], m * 8 + k) * wk;
        }
    }
    #pragma unroll
    for (int r = 0; r < 4; r++)
        if (i0 + r < n) out[(size_t)(i0 + r) * 64 + lane] = f2bf(fmaxf(acc[r], 0.f));
}

__global__ void k_final(const float* __restrict__ x, const float* __restrict__ W,
                        const float* __restrict__ b, float* __restrict__ out, int n) {
    int t = blockIdx.x * blockDim.x + threadIdx.x;
    if (t >= n * 8) return;
    int i = t >> 3, o = t & 7;
    float acc = b[o];
    #pragma unroll 8
    for (int k = 0; k < 64; k++) acc += fmaxf(x[i * 64 + k], 0.f) * W[k * 8 + o];
    out[t] = acc;
}

static inline unsigned gblk(long long n) { return (unsigned)((n + BLK - 1) / BLK); }
static inline unsigned gwv4(long long n) { return gblk(((n + 3) / 4) * 64); }
static inline unsigned gwv1(long long n) { return gblk(n * 64); }

extern "C" void kernel_launch(void* const* d_in, const int* in_sizes, int n_in,
                              void* d_out, int out_size, void* d_ws, size_t ws_size,
                              hipStream_t stream) {
    const float* game_x  = (const float*)d_in[0];
    const float* state_x = (const float*)d_in[1];
    const int*   ei_vv   = (const int*)d_in[2];
    const int*   ei_h    = (const int*)d_in[3];
    const float* ea_h    = (const float*)d_in[4];
    const int*   ei_in   = (const int*)d_in[5];
    const int*   ei_ss   = (const int*)d_in[6];
    const float* tag1_W  = (const float*)d_in[7];
    const float* tag1_b  = (const float*)d_in[8];
    const float* tag2_W  = (const float*)d_in[9];
    const float* tag2_b  = (const float*)d_in[10];
    const float* gc_Wrel = (const float*)d_in[11];
    const float* gc_b    = (const float*)d_in[12];
    const float* gc_Wroot= (const float*)d_in[13];
    const float* sage_Wl = (const float*)d_in[14];
    const float* sage_bl = (const float*)d_in[15];
    const float* sage_Wr = (const float*)d_in[16];
    const float* lin_W   = (const float*)d_in[17];
    const float* lin_b   = (const float*)d_in[18];

    const int NV  = in_sizes[0] / 5;
    const int NS  = in_sizes[1] / 6;
    const int EVV = in_sizes[2] / 2;
    const int EH  = in_sizes[3] / 2;
    const int EIN = in_sizes[5] / 2;
    const int ESS = in_sizes[6] / 2;

    const int *vv_s = ei_vv,  *vv_d = ei_vv + EVV;
    const int *h_s  = ei_h,   *h_d  = ei_h  + EH;
    const int *in_s = ei_in,  *in_d = ei_in + EIN;
    const int *ss_s = ei_ss,  *ss_d = ei_ss + ESS;

    // ---------------- workspace layout (4-byte words), ~77 MB ----------------
    float* wsf = (float*)d_ws;
    size_t o = 0;
    unsigned short* gx_bf = (unsigned short*)(wsf + o); o += (size_t)NV * 32;  // NV x 64 bf16
    float* sx3 = wsf + o; o += (size_t)NS * 64;                                // fp32 (separate: k_bc writes while gx live)
    unsigned short* hA_bf = (unsigned short*)(wsf + o); o += (size_t)NS * 32;
    unsigned short* hB_bf = (unsigned short*)(wsf + o); o += (size_t)NS * 32;
    float* B4 = wsf + o; o += (size_t)NS * 32;   // h1v+h2v (NV*10) | sx2_bf (NS*32)
    int*  vvsrc = (int*)(wsf + o); o += (size_t)EVV;
    int*  sssrc = (int*)(wsf + o); o += (size_t)ESS;
    int*  insrc = (int*)(wsf + o); o += (size_t)EIN;
    int2* hsw   = (int2*)(wsf + o); o += (size_t)EH * 2;
    unsigned short* rkv = (unsigned short*)(wsf + o);
    unsigned short* rkh = rkv + EVV;
    unsigned short* rki = rkh + EH;
    unsigned short* rks = rki + EIN;
    o += ((size_t)EVV + EH + EIN + ESS + 1) / 2;
    int* cv = (int*)(wsf + o);
    int* ch = cv + NV;
    int* ci = ch + NS;
    int* cs = ci + NS;
    int* rv = cs + NS;            // NV+1
    int* rh = rv + NV + 1;        // NS+1
    int* ri = rh + NS + 1;        // NS+1
    int* rs = ri + NS + 1;        // NS+1
    float* dinv_v = (float*)(rs + NS + 1);  // NV
    float* dinv_s = dinv_v + NV;            // NS
    int* bsum = (int*)(dinv_s + NS);        // up to 1024

    unsigned short* sx2_bf = (unsigned short*)B4;

    // ================= Phase 0: batched CSR build =================
    hipMemsetAsync(cv, 0, (size_t)(NV + 3 * NS) * sizeof(int), stream);
    long long Etot = (long long)EVV + EH + EIN + ESS;
    k_hist_all<<<gblk(Etot), BLK, 0, stream>>>(vv_d, h_d, in_d, ss_d, cv, ch, ci, cs,
                                               rkv, rkh, rki, rks, EVV, EH, EIN, ESS);
    int nbv = (NV + 255) / 256, nbs = (NS + 255) / 256;
    int NB = nbv + 3 * nbs;
    k_scanb_all<<<NB, 256, 0, stream>>>(cv, ch, ci, cs, rv, rh, ri, rs,
                                        dinv_v, dinv_s, bsum, NV, NS, nbv, nbs);
    k_scant_all<<<4, 1024, 0, stream>>>(bsum, nbv, nbs);
    k_scana_all<<<NB, 256, 0, stream>>>(rv, rh, ri, rs, bsum,
                                        NV, NS, nbv, nbs, EVV, EH, EIN, ESS);
    k_fill_all<<<gblk(Etot), BLK, 0, stream>>>(
        vv_s, vv_d, rkv, rv, vvsrc,
        h_s, h_d, ea_h, rkh, rh, hsw,
        in_s, in_d, rki, ri, insrc,
        ss_s, ss_d, rks, rs, sssrc,
        EVV, EH, EIN, ESS);

    // ================= Stage A: TAGConv1 on v-v =================
    float* h1v = B4;
    float* h2v = B4 + (size_t)NV * 5;
    k_gather5<<<gblk(NV), BLK, 0, stream>>>(game_x, rv, vvsrc, dinv_v, h1v, NV);
    k_gather5<<<gblk(NV), BLK, 0, stream>>>(h1v,    rv, vvsrc, dinv_v, h2v, NV);
    k_tag1_w<<<gwv4(NV), BLK, 0, stream>>>(game_x, h1v, h2v, tag1_W, tag1_b, gx_bf, NV);

    // ================= Stage B+C fused: GraphConv + SAGE + TAG2-W0 =================
    k_bc<<<gwv1(NS), BLK, 0, stream>>>(gx_bf, rh, hsw, ri, insrc, state_x,
                                       gc_Wrel, gc_Wroot, gc_b,
                                       sage_Wl, sage_Wr, sage_bl,
                                       tag2_W, tag2_b, sx2_bf, sx3, NS);

    // ================= Stage D: 3 fused hops =================
    k_hop<<<gwv1(NS), BLK, 0, stream>>>(sx2_bf, rs, sssrc, dinv_s, tag2_W + 4096,  hA_bf, sx3, NS);
    k_hop<<<gwv1(NS), BLK, 0, stream>>>(hA_bf,  rs, sssrc, dinv_s, tag2_W + 8192,  hB_bf, sx3, NS);
    k_hop<<<gwv1(NS), BLK, 0, stream>>>(hB_bf,  rs, sssrc, dinv_s, tag2_W + 12288, hA_bf, sx3, NS);

    // ================= Stage E: final linear (relu fused) =================
    k_final<<<gblk((long long)NS * 8), BLK, 0, stream>>>(sx3, lin_W, lin_b, (float*)d_out, NS);
}

// Round 10
// 632.695 us; speedup vs baseline: 1.0109x; 1.0109x over previous
//
#include <hip/hip_runtime.h>

#define BLK 256

__device__ __forceinline__ float bcast(float v, int l) {
    return __int_as_float(__builtin_amdgcn_readlane(__float_as_int(v), l));
}
__device__ __forceinline__ unsigned short f2bf(float f) {
    unsigned u = __float_as_uint(f);
    return (unsigned short)((u + 0x7FFFu + ((u >> 16) & 1u)) >> 16);
}
__device__ __forceinline__ float bf2f(unsigned short b) {
    return __uint_as_float(((unsigned)b) << 16);
}

// ================= batched CSR skeleton (all 4 graphs) =================

__global__ void k_hist_all(const int* __restrict__ dv, const int* __restrict__ dh,
                           const int* __restrict__ di, const int* __restrict__ ds,
                           int* __restrict__ cv, int* __restrict__ ch,
                           int* __restrict__ ci, int* __restrict__ cs,
                           unsigned short* __restrict__ rkv, unsigned short* __restrict__ rkh,
                           unsigned short* __restrict__ rki, unsigned short* __restrict__ rks,
                           int Ev, int Eh, int Ei, int Es) {
    int e = blockIdx.x * blockDim.x + threadIdx.x;
    if (e < Ev) { rkv[e] = (unsigned short)atomicAdd(&cv[dv[e]], 1); return; }
    e -= Ev;
    if (e < Eh) { rkh[e] = (unsigned short)atomicAdd(&ch[dh[e]], 1); return; }
    e -= Eh;
    if (e < Ei) { rki[e] = (unsigned short)atomicAdd(&ci[di[e]], 1); return; }
    e -= Ei;
    if (e < Es) rks[e] = (unsigned short)atomicAdd(&cs[ds[e]], 1);
}

// batched block scan; emits dinv=rsqrt(deg) and sdeg=sqrt(deg) for vv/ss graphs
__global__ void k_scanb_all(const int* __restrict__ cv, const int* __restrict__ ch,
                            const int* __restrict__ ci, const int* __restrict__ cs,
                            int* __restrict__ rv, int* __restrict__ rh,
                            int* __restrict__ ri, int* __restrict__ rs,
                            float* __restrict__ dv, float* __restrict__ ds,
                            float* __restrict__ sv, float* __restrict__ ss2,
                            int* __restrict__ bsum, int nv, int ns, int nbv, int nbs) {
    __shared__ int sh[256];
    int blk = blockIdx.x;
    const int* cnt; int* rp; float* dinv; float* sdeg; int n; int lb;
    if (blk < nbv)                { cnt = cv; rp = rv; dinv = dv; sdeg = sv;   n = nv; lb = blk; }
    else if (blk < nbv + nbs)     { cnt = ch; rp = rh; dinv = nullptr; sdeg = nullptr; n = ns; lb = blk - nbv; }
    else if (blk < nbv + 2 * nbs) { cnt = ci; rp = ri; dinv = nullptr; sdeg = nullptr; n = ns; lb = blk - nbv - nbs; }
    else                          { cnt = cs; rp = rs; dinv = ds; sdeg = ss2;  n = ns; lb = blk - nbv - 2 * nbs; }
    int i = lb * 256 + threadIdx.x;
    int v = (i < n) ? cnt[i] : 0;
    if (dinv && i < n) {
        dinv[i] = v > 0 ? rsqrtf((float)v) : 0.f;
        sdeg[i] = v > 0 ? sqrtf((float)v) : 0.f;
    }
    sh[threadIdx.x] = v; __syncthreads();
    for (int off = 1; off < 256; off <<= 1) {
        int t = (threadIdx.x >= off) ? sh[threadIdx.x - off] : 0;
        __syncthreads();
        sh[threadIdx.x] += t; __syncthreads();
    }
    if (i < n) rp[i] = sh[threadIdx.x] - v;
    if (threadIdx.x == 255) bsum[blk] = sh[255];
}

__global__ void k_scant_all(int* __restrict__ bsum, int nbv, int nbs) {
    __shared__ int sh[1024];
    int g = blockIdx.x;
    int off = (g == 0) ? 0 : nbv + (g - 1) * nbs;
    int nb  = (g == 0) ? nbv : nbs;
    int tid = threadIdx.x;
    int v = (tid < nb) ? bsum[off + tid] : 0;
    sh[tid] = v; __syncthreads();
    for (int o2 = 1; o2 < 1024; o2 <<= 1) {
        int t = (tid >= o2) ? sh[tid - o2] : 0;
        __syncthreads();
        sh[tid] += t; __syncthreads();
    }
    if (tid < nb) bsum[off + tid] = sh[tid] - v;
}

__global__ void k_scana_all(int* __restrict__ rv, int* __restrict__ rh,
                            int* __restrict__ ri, int* __restrict__ rs,
                            const int* __restrict__ bsum, int nv, int ns, int nbv, int nbs,
                            int Ev, int Eh, int Ei, int Es) {
    int blk = blockIdx.x;
    int* rp; int n; int lb; int E;
    if (blk < nbv)                { rp = rv; n = nv; lb = blk;               E = Ev; }
    else if (blk < nbv + nbs)     { rp = rh; n = ns; lb = blk - nbv;         E = Eh; }
    else if (blk < nbv + 2 * nbs) { rp = ri; n = ns; lb = blk - nbv - nbs;   E = Ei; }
    else                          { rp = rs; n = ns; lb = blk - nbv - 2*nbs; E = Es; }
    int i = lb * 256 + threadIdx.x;
    if (i < n) rp[i] += bsum[blk];
    if (i == 0) rp[n] = E;
}

__global__ void k_fill_all(
    const int* __restrict__ vv_s, const int* __restrict__ vv_d,
    const unsigned short* __restrict__ rkv, const int* __restrict__ rv, int* __restrict__ vvsrc,
    const int* __restrict__ h_s, const int* __restrict__ h_d, const float* __restrict__ hw,
    const unsigned short* __restrict__ rkh, const int* __restrict__ rh, int2* __restrict__ hsw,
    const int* __restrict__ in_s, const int* __restrict__ in_d,
    const unsigned short* __restrict__ rki, const int* __restrict__ ri, int* __restrict__ insrc,
    const int* __restrict__ ss_s, const int* __restrict__ ss_d,
    const unsigned short* __restrict__ rks, const int* __restrict__ rs, int* __restrict__ sssrc,
    int Ev, int Eh, int Ei, int Es) {
    int e = blockIdx.x * blockDim.x + threadIdx.x;
    if (e < Ev) { vvsrc[rv[vv_d[e]] + rkv[e]] = vv_s[e]; return; }
    e -= Ev;
    if (e < Eh) { hsw[rh[h_d[e]] + rkh[e]] = make_int2(h_s[e], __float_as_int(hw[e])); return; }
    e -= Eh;
    if (e < Ei) { insrc[ri[in_d[e]] + rki[e]] = in_s[e]; return; }
    e -= Ei;
    if (e < Es) sssrc[rs[ss_d[e]] + rks[e]] = ss_s[e];
}

// ================= stage A: pre-scale + padded-8 gathers =================

// gxs8[i][k] = k<5 ? game_x[i][k]*dinv_v[i] : 0
__global__ void k_prescale5(const float* __restrict__ x, const float* __restrict__ dinv,
                            float* __restrict__ out8, int n) {
    int t = blockIdx.x * blockDim.x + threadIdx.x;
    if (t >= n * 8) return;
    int i = t >> 3, k = t & 7;
    out8[t] = (k < 5) ? x[(size_t)i * 5 + k] * dinv[i] : 0.f;
}

// plain-sum gather over padded-8 rows; out = dd^POW * sum. Thread per dst, 4-edge unroll.
template<int POW>
__global__ void k_gather5p(const float* __restrict__ x8, const int* __restrict__ rowptr,
                           const int* __restrict__ csr_src, const float* __restrict__ dinv,
                           float* __restrict__ out8, int n) {
    int d = blockIdx.x * blockDim.x + threadIdx.x;
    if (d >= n) return;
    int b = rowptr[d], e = rowptr[d + 1];
    float4 aL = make_float4(0,0,0,0), aH = make_float4(0,0,0,0);
    int p = b;
    for (; p + 4 <= e; p += 4) {
        int s0 = csr_src[p], s1 = csr_src[p+1], s2 = csr_src[p+2], s3 = csr_src[p+3];
        const float4* x0 = (const float4*)(x8 + (size_t)s0 * 8);
        const float4* x1 = (const float4*)(x8 + (size_t)s1 * 8);
        const float4* x2 = (const float4*)(x8 + (size_t)s2 * 8);
        const float4* x3 = (const float4*)(x8 + (size_t)s3 * 8);
        float4 l0 = x0[0], h0 = x0[1], l1 = x1[0], h1 = x1[1];
        float4 l2 = x2[0], h2 = x2[1], l3 = x3[0], h3 = x3[1];
        aL.x += l0.x + l1.x + l2.x + l3.x;  aL.y += l0.y + l1.y + l2.y + l3.y;
        aL.z += l0.z + l1.z + l2.z + l3.z;  aL.w += l0.w + l1.w + l2.w + l3.w;
        aH.x += h0.x + h1.x + h2.x + h3.x;  // only lane 4 (index 4) matters in high half
    }
    for (; p < e; p++) {
        int s = csr_src[p];
        const float4* xp = (const float4*)(x8 + (size_t)s * 8);
        float4 l = xp[0], h = xp[1];
        aL.x += l.x; aL.y += l.y; aL.z += l.z; aL.w += l.w;
        aH.x += h.x;
    }
    float dd = dinv[d];
    float sc = (POW == 2) ? dd * dd : dd;
    float4 oL = make_float4(aL.x * sc, aL.y * sc, aL.z * sc, aL.w * sc);
    float4 oH = make_float4(aH.x * sc, 0.f, 0.f, 0.f);
    ((float4*)(out8 + (size_t)d * 8))[0] = oL;
    ((float4*)(out8 + (size_t)d * 8))[1] = oH;
}

// ================= 64-ch gather (bf16 rows, pure sum) =================
// MODE: 0 = plain sum, 1 = per-edge weight (int2 packed). POW: post-scale dd^POW.
// OUTBF: write bf16 row, else fp32.
template<int MODE, int POW, bool OUTBF>
__global__ void k_gather64(const unsigned short* __restrict__ xbf, const int* __restrict__ rowptr,
                           const int* __restrict__ csr_src, const int2* __restrict__ csr_sw,
                           const float* __restrict__ dinv, void* __restrict__ outp, int n) {
    int wid = (int)(((long long)blockIdx.x * blockDim.x + threadIdx.x) >> 6);
    if (wid >= n) return;
    int lane = threadIdx.x & 63;
    int g = lane >> 4, q = lane & 15;
    int b = rowptr[wid], e = rowptr[wid + 1];
    float4 acc = make_float4(0.f, 0.f, 0.f, 0.f);
    int p = b + g;
    for (; p + 12 < e; p += 16) {
        int s0, s1, s2, s3;
        float w0 = 1.f, w1 = 1.f, w2 = 1.f, w3 = 1.f;
        if (MODE == 1) {
            int2 e0 = csr_sw[p], e1 = csr_sw[p+4], e2 = csr_sw[p+8], e3 = csr_sw[p+12];
            s0 = e0.x; w0 = __int_as_float(e0.y);
            s1 = e1.x; w1 = __int_as_float(e1.y);
            s2 = e2.x; w2 = __int_as_float(e2.y);
            s3 = e3.x; w3 = __int_as_float(e3.y);
        } else {
            s0 = csr_src[p]; s1 = csr_src[p+4]; s2 = csr_src[p+8]; s3 = csr_src[p+12];
        }
        ushort4 u0 = ((const ushort4*)(xbf + (size_t)s0 * 64))[q];
        ushort4 u1 = ((const ushort4*)(xbf + (size_t)s1 * 64))[q];
        ushort4 u2 = ((const ushort4*)(xbf + (size_t)s2 * 64))[q];
        ushort4 u3 = ((const ushort4*)(xbf + (size_t)s3 * 64))[q];
        if (MODE == 0) {
            acc.x += bf2f(u0.x) + bf2f(u1.x) + bf2f(u2.x) + bf2f(u3.x);
            acc.y += bf2f(u0.y) + bf2f(u1.y) + bf2f(u2.y) + bf2f(u3.y);
            acc.z += bf2f(u0.z) + bf2f(u1.z) + bf2f(u2.z) + bf2f(u3.z);
            acc.w += bf2f(u0.w) + bf2f(u1.w) + bf2f(u2.w) + bf2f(u3.w);
        } else {
            acc.x += bf2f(u0.x)*w0 + bf2f(u1.x)*w1 + bf2f(u2.x)*w2 + bf2f(u3.x)*w3;
            acc.y += bf2f(u0.y)*w0 + bf2f(u1.y)*w1 + bf2f(u2.y)*w2 + bf2f(u3.y)*w3;
            acc.z += bf2f(u0.z)*w0 + bf2f(u1.z)*w1 + bf2f(u2.z)*w2 + bf2f(u3.z)*w3;
            acc.w += bf2f(u0.w)*w0 + bf2f(u1.w)*w1 + bf2f(u2.w)*w2 + bf2f(u3.w)*w3;
        }
    }
    for (; p < e; p += 4) {
        int s; float w = 1.f;
        if (MODE == 1) { int2 e0 = csr_sw[p]; s = e0.x; w = __int_as_float(e0.y); }
        else s = csr_src[p];
        ushort4 u = ((const ushort4*)(xbf + (size_t)s * 64))[q];
        acc.x += bf2f(u.x)*w; acc.y += bf2f(u.y)*w;
        acc.z += bf2f(u.z)*w; acc.w += bf2f(u.w)*w;
    }
    #pragma unroll
    for (int off = 16; off < 64; off <<= 1) {
        acc.x += __shfl_xor(acc.x, off, 64);
        acc.y += __shfl_xor(acc.y, off, 64);
        acc.z += __shfl_xor(acc.z, off, 64);
        acc.w += __shfl_xor(acc.w, off, 64);
    }
    if (g == 0) {
        if (POW == 2) { float dd = dinv[wid]; float sc = dd * dd;
                        acc.x *= sc; acc.y *= sc; acc.z *= sc; acc.w *= sc; }
        if (OUTBF) {
            ushort4 ov;
            ov.x = f2bf(acc.x); ov.y = f2bf(acc.y); ov.z = f2bf(acc.z); ov.w = f2bf(acc.w);
            ((ushort4*)outp)[(size_t)wid * 16 + q] = ov;
        } else {
            ((float4*)outp)[(size_t)wid * 16 + q] = acc;
        }
    }
}

// ================= dense combines (4-row wave-tiled register GEMMs) =================

// gx_bf = bf16(relu(b + x@W0 + (h1s*sdeg)@W1 + h2@W2))
__global__ __launch_bounds__(256, 4)
void k_tag1_w(const float* __restrict__ x, const float* __restrict__ h1s8,
              const float* __restrict__ h2_8, const float* __restrict__ sdeg,
              const float* __restrict__ W, const float* __restrict__ b,
              unsigned short* __restrict__ out, int n) {
    int wv = (int)(((long long)blockIdx.x * blockDim.x + threadIdx.x) >> 6);
    int lane = threadIdx.x & 63;
    int i0 = wv * 4;
    if (i0 >= n) return;
    float v[4], acc[4];
    #pragma unroll
    for (int r = 0; r < 4; r++) {
        int i = (i0 + r < n) ? i0 + r : n - 1;
        float t = 0.f;
        if (lane < 5)                     t = x[(size_t)i * 5 + lane];
        else if (lane >= 8 && lane < 13)  t = h1s8[(size_t)i * 8 + lane - 8] * sdeg[i];
        else if (lane >= 16 && lane < 21) t = h2_8[(size_t)i * 8 + lane - 16];
        v[r] = t;
        acc[r] = b[lane];
    }
    #pragma unroll
    for (int m = 0; m < 3; m++) {
        #pragma unroll
        for (int k = 0; k < 5; k++) {
            float wk = W[(m * 5 + k) * 64 + lane];
            #pragma unroll
            for (int r = 0; r < 4; r++) acc[r] += bcast(v[r], m * 8 + k) * wk;
        }
    }
    #pragma unroll
    for (int r = 0; r < 4; r++)
        if (i0 + r < n) out[(size_t)(i0 + r) * 64 + lane] = f2bf(fmaxf(acc[r], 0.f));
}

// sx = relu(b + agg@Wrel + state@Wroot)
__global__ __launch_bounds__(256, 4)
void k_gc_w(const float* __restrict__ agg, const float* __restrict__ st,
            const float* __restrict__ Wrel, const float* __restrict__ Wroot,
            const float* __restrict__ b, float* __restrict__ out, int n) {
    int wv = (int)(((long long)blockIdx.x * blockDim.x + threadIdx.x) >> 6);
    int lane = threadIdx.x & 63;
    int i0 = wv * 4;
    if (i0 >= n) return;
    float xs[4], sr[4], acc[4];
    #pragma unroll
    for (int r = 0; r < 4; r++) {
        int i = (i0 + r < n) ? i0 + r : n - 1;
        xs[r] = agg[(size_t)i * 64 + lane];
        sr[r] = (lane < 6) ? st[(size_t)i * 6 + lane] : 0.f;
        acc[r] = b[lane];
    }
    #pragma unroll 8
    for (int k = 0; k < 64; k++) {
        float wk = Wrel[k * 64 + lane];
        #pragma unroll
        for (int r = 0; r < 4; r++) acc[r] += bcast(xs[r], k) * wk;
    }
    #pragma unroll
    for (int k = 0; k < 6; k++) {
        float wk = Wroot[k * 64 + lane];
        #pragma unroll
        for (int r = 0; r < 4; r++) acc[r] += bcast(sr[r], k) * wk;
    }
    #pragma unroll
    for (int r = 0; r < 4; r++)
        if (i0 + r < n) out[(size_t)(i0 + r) * 64 + lane] = fmaxf(acc[r], 0.f);
}

// sx2s_bf = bf16( relu(bl + (ssum/cnt)@Wl + sx@Wr) * dinv_s[i] )   (pre-scaled for hop1)
__global__ __launch_bounds__(256, 4)
void k_sage_w(const float* __restrict__ ssum, const int* __restrict__ rp,
              const float* __restrict__ sx, const float* __restrict__ dinv,
              const float* __restrict__ Wl, const float* __restrict__ Wr,
              const float* __restrict__ bl, unsigned short* __restrict__ out, int n) {
    int wv = (int)(((long long)blockIdx.x * blockDim.x + threadIdx.x) >> 6);
    int lane = threadIdx.x & 63;
    int i0 = wv * 4;
    if (i0 >= n) return;
    float xs[4], ys[4], acc[4];
    #pragma unroll
    for (int r = 0; r < 4; r++) {
        int i = (i0 + r < n) ? i0 + r : n - 1;
        float cnt = (float)(rp[i + 1] - rp[i]);
        float rs = 1.f / fmaxf(cnt, 1.f);
        xs[r] = ssum[(size_t)i * 64 + lane] * rs;
        ys[r] = sx[(size_t)i * 64 + lane];
        acc[r] = bl[lane];
    }
    #pragma unroll 8
    for (int k = 0; k < 64; k++) {
        float wl = Wl[k * 64 + lane];
        float wr = Wr[k * 64 + lane];
        #pragma unroll
        for (int r = 0; r < 4; r++)
            acc[r] += bcast(xs[r], k) * wl + bcast(ys[r], k) * wr;
    }
    #pragma unroll
    for (int r = 0; r < 4; r++)
        if (i0 + r < n)
            out[(size_t)(i0 + r) * 64 + lane] = f2bf(fmaxf(acc[r], 0.f) * dinv[i0 + r]);
}

// INIT: out = bias + (x*rowscale)@W ; else out += (x*rowscale)@W
// x rows bf16 pre-scaled; rowscale = sdeg (unscales)
template<bool INIT>
__global__ __launch_bounds__(256, 4)
void k_mm_w(const unsigned short* __restrict__ xbf, const float* __restrict__ rowscale,
            const float* __restrict__ W, const float* __restrict__ bias,
            float* __restrict__ out, int n) {
    int wv = (int)(((long long)blockIdx.x * blockDim.x + threadIdx.x) >> 6);
    int lane = threadIdx.x & 63;
    int i0 = wv * 4;
    if (i0 >= n) return;
    float xs[4], acc[4];
    #pragma unroll
    for (int r = 0; r < 4; r++) {
        int i = (i0 + r < n) ? i0 + r : n - 1;
        xs[r] = bf2f(xbf[(size_t)i * 64 + lane]) * rowscale[i];
        acc[r] = INIT ? bias[lane] : out[(size_t)i * 64 + lane];
    }
    #pragma unroll 8
    for (int k = 0; k < 64; k++) {
        float wk = W[k * 64 + lane];
        #pragma unroll
        for (int r = 0; r < 4; r++) acc[r] += bcast(xs[r], k) * wk;
    }
    #pragma unroll
    for (int r = 0; r < 4; r++)
        if (i0 + r < n) out[(size_t)(i0 + r) * 64 + lane] = acc[r];
}

__global__ void k_final(const float* __restrict__ x, const float* __restrict__ W,
                        const float* __restrict__ b, float* __restrict__ out, int n) {
    int t = blockIdx.x * blockDim.x + threadIdx.x;
    if (t >= n * 8) return;
    int i = t >> 3, o = t & 7;
    float acc = b[o];
    #pragma unroll 8
    for (int k = 0; k < 64; k++) acc += fmaxf(x[i * 64 + k], 0.f) * W[k * 8 + o];
    out[t] = acc;
}

static inline unsigned gblk(long long n) { return (unsigned)((n + BLK - 1) / BLK); }
static inline unsigned gwv4(long long n) { return gblk(((n + 3) / 4) * 64); }
static inline unsigned gwv1(long long n) { return gblk(n * 64); }

extern "C" void kernel_launch(void* const* d_in, const int* in_sizes, int n_in,
                              void* d_out, int out_size, void* d_ws, size_t ws_size,
                              hipStream_t stream) {
    const float* game_x  = (const float*)d_in[0];
    const float* state_x = (const float*)d_in[1];
    const int*   ei_vv   = (const int*)d_in[2];
    const int*   ei_h    = (const int*)d_in[3];
    const float* ea_h    = (const float*)d_in[4];
    const int*   ei_in   = (const int*)d_in[5];
    const int*   ei_ss   = (const int*)d_in[6];
    const float* tag1_W  = (const float*)d_in[7];
    const float* tag1_b  = (const float*)d_in[8];
    const float* tag2_W  = (const float*)d_in[9];
    const float* tag2_b  = (const float*)d_in[10];
    const float* gc_Wrel = (const float*)d_in[11];
    const float* gc_b    = (const float*)d_in[12];
    const float* gc_Wroot= (const float*)d_in[13];
    const float* sage_Wl = (const float*)d_in[14];
    const float* sage_bl = (const float*)d_in[15];
    const float* sage_Wr = (const float*)d_in[16];
    const float* lin_W   = (const float*)d_in[17];
    const float* lin_b   = (const float*)d_in[18];

    const int NV  = in_sizes[0] / 5;
    const int NS  = in_sizes[1] / 6;
    const int EVV = in_sizes[2] / 2;
    const int EH  = in_sizes[3] / 2;
    const int EIN = in_sizes[5] / 2;
    const int ESS = in_sizes[6] / 2;

    const int *vv_s = ei_vv,  *vv_d = ei_vv + EVV;
    const int *h_s  = ei_h,   *h_d  = ei_h  + EH;
    const int *in_s = ei_in,  *in_d = ei_in + EIN;
    const int *ss_s = ei_ss,  *ss_d = ei_ss + ESS;

    // ---------------- workspace layout (4-byte words), ~73 MB ----------------
    float* wsf = (float*)d_ws;
    size_t o = 0;
    unsigned short* gx_bf = (unsigned short*)(wsf + o); o += (size_t)NV * 32; // later: sx2s_bf (NS*32 words needed; NV*32 available)
    float* P1 = wsf + o; o += (size_t)NS * 64;   // agg | ssum, later sx3
    float* P2 = wsf + o; o += (size_t)NS * 64;   // sx, later hA_bf + hB_bf
    float* gxs8 = wsf + o; o += (size_t)NV * 8;  // later h2_8
    float* h1s8 = wsf + o; o += (size_t)NV * 8;
    int*  vvsrc = (int*)(wsf + o); o += (size_t)EVV;
    int*  sssrc = (int*)(wsf + o); o += (size_t)ESS;
    int*  insrc = (int*)(wsf + o); o += (size_t)EIN;
    int2* hsw   = (int2*)(wsf + o); o += (size_t)EH * 2;
    unsigned short* rkv = (unsigned short*)(wsf + o);
    unsigned short* rkh = rkv + EVV;
    unsigned short* rki = rkh + EH;
    unsigned short* rks = rki + EIN;
    o += ((size_t)EVV + EH + EIN + ESS + 1) / 2;
    int* cv = (int*)(wsf + o);
    int* ch = cv + NV;
    int* ci = ch + NS;
    int* cs = ci + NS;
    int* rv = cs + NS;            // NV+1
    int* rh = rv + NV + 1;        // NS+1
    int* ri = rh + NS + 1;        // NS+1
    int* rs = ri + NS + 1;        // NS+1
    float* dinv_v = (float*)(rs + NS + 1);  // NV
    float* dinv_s = dinv_v + NV;            // NS
    float* sdeg_v = dinv_s + NS;            // NV
    float* sdeg_s = sdeg_v + NV;            // NS
    int* bsum = (int*)(sdeg_s + NS);        // up to 1024

    float* h2_8 = gxs8;                           // gxs dead after gather5 #1
    unsigned short* sx2s_bf = gx_bf;              // gx dead after stage-B/C gathers
    float* sx3 = P1;                              // agg/ssum dead after sage
    unsigned short* hA_bf = (unsigned short*)P2;  // sx dead after sage
    unsigned short* hB_bf = hA_bf + (size_t)NS * 64;

    // ================= Phase 0: batched CSR build =================
    hipMemsetAsync(cv, 0, (size_t)(NV + 3 * NS) * sizeof(int), stream);
    long long Etot = (long long)EVV + EH + EIN + ESS;
    k_hist_all<<<gblk(Etot), BLK, 0, stream>>>(vv_d, h_d, in_d, ss_d, cv, ch, ci, cs,
                                               rkv, rkh, rki, rks, EVV, EH, EIN, ESS);
    int nbv = (NV + 255) / 256, nbs = (NS + 255) / 256;
    int NB = nbv + 3 * nbs;
    k_scanb_all<<<NB, 256, 0, stream>>>(cv, ch, ci, cs, rv, rh, ri, rs,
                                        dinv_v, dinv_s, sdeg_v, sdeg_s,
                                        bsum, NV, NS, nbv, nbs);
    k_scant_all<<<4, 1024, 0, stream>>>(bsum, nbv, nbs);
    k_scana_all<<<NB, 256, 0, stream>>>(rv, rh, ri, rs, bsum,
                                        NV, NS, nbv, nbs, EVV, EH, EIN, ESS);
    k_fill_all<<<gblk(Etot), BLK, 0, stream>>>(
        vv_s, vv_d, rkv, rv, vvsrc,
        h_s, h_d, ea_h, rkh, rh, hsw,
        in_s, in_d, rki, ri, insrc,
        ss_s, ss_d, rks, rs, sssrc,
        EVV, EH, EIN, ESS);

    // ================= Stage A: TAGConv1 on v-v (pre-scaled, padded-8) =====
    k_prescale5<<<gblk((long long)NV * 8), BLK, 0, stream>>>(game_x, dinv_v, gxs8, NV);
    // h1s8 = dinv[d]^2 * sum(gxs8)  (= dinv[d]*h1, pre-scaled for next hop)
    k_gather5p<2><<<gblk(NV), BLK, 0, stream>>>(gxs8, rv, vvsrc, dinv_v, h1s8, NV);
    // h2_8 = dinv[d] * sum(h1s8)    (= h2, unscaled; overwrites gxs8)
    k_gather5p<1><<<gblk(NV), BLK, 0, stream>>>(h1s8, rv, vvsrc, dinv_v, h2_8, NV);
    k_tag1_w<<<gwv4(NV), BLK, 0, stream>>>(game_x, h1s8, h2_8, sdeg_v, tag1_W, tag1_b, gx_bf, NV);

    // ================= Stage B: GraphConv (weighted) =================
    k_gather64<1, 0, false><<<gwv1(NS), BLK, 0, stream>>>(gx_bf, rh, nullptr, hsw, nullptr, P1, NS);
    k_gc_w<<<gwv4(NS), BLK, 0, stream>>>(P1, state_x, gc_Wrel, gc_Wroot, gc_b, P2, NS);

    // ================= Stage C: SAGE mean =================
    k_gather64<0, 0, false><<<gwv1(NS), BLK, 0, stream>>>(gx_bf, ri, insrc, nullptr, nullptr, P1, NS);
    k_sage_w<<<gwv4(NS), BLK, 0, stream>>>(P1, ri, P2, dinv_s, sage_Wl, sage_Wr, sage_bl, sx2s_bf, NS);

    // ================= Stage D: TAGConv2 on s-s (K=3, pre-scaled hops) =====
    k_mm_w<true><<<gwv4(NS), BLK, 0, stream>>>(sx2s_bf, sdeg_s, tag2_W, tag2_b, sx3, NS);
    k_gather64<0, 2, true><<<gwv1(NS), BLK, 0, stream>>>(sx2s_bf, rs, sssrc, nullptr, dinv_s, hA_bf, NS);
    k_mm_w<false><<<gwv4(NS), BLK, 0, stream>>>(hA_bf, sdeg_s, tag2_W + 4096, nullptr, sx3, NS);
    k_gather64<0, 2, true><<<gwv1(NS), BLK, 0, stream>>>(hA_bf, rs, sssrc, nullptr, dinv_s, hB_bf, NS);
    k_mm_w<false><<<gwv4(NS), BLK, 0, stream>>>(hB_bf, sdeg_s, tag2_W + 8192, nullptr, sx3, NS);
    k_gather64<0, 2, true><<<gwv1(NS), BLK, 0, stream>>>(hB_bf, rs, sssrc, nullptr, dinv_s, hA_bf, NS);
    k_mm_w<false><<<gwv4(NS), BLK, 0, stream>>>(hA_bf, sdeg_s, tag2_W + 12288, nullptr, sx3, NS);

    // ================= Stage E: final linear (relu fused) =================
    k_final<<<gblk((long long)NS * 8), BLK, 0, stream>>>(sx3, lin_W, lin_b, (float*)d_out, NS);
}